// Round 4
// baseline (279.028 us; speedup 1.0000x reference)
//
#include <hip/hip_runtime.h>
#include <stdint.h>

// Encoder: out[n][0] = x[n]; out[n][1+i] = square(2*pi * x[n] * 2^i), i=0..14.
//
// Bit-exact replication of the f32 JAX reference:
//   t = RN32(f32(2pi) * x); p = t * 2^i (exact pow2 scale);
//   sq = fmodf(p, f32(2pi)) < f32(pi) ? +1 : -1.
// f32(2pi) = M*2^-21, f32(pi) = M*2^-22, M = 13176795 (same 24-bit mantissa).
// With t = mant*2^(E-23):  fmod(t*2^i, 2pif) < pif  <=>  floor(t*2^i/pif) even
//   <=>  bit (E-1+i) of the binary expansion of mant/M is 0.
// q = floor(mant*2^15 / M) (exact via magic multiply: err < 2^-24 < 1/M) holds
// those bits; q < 2^16, so clamping the shift to 31 yields bit=0 for any
// out-of-range index (covers x=0 / tiny x where E is very negative).
//
// Perf model (R3 post-mortem): dur_us includes ~217 us of harness poison /
// restore fills (1 GiB ws poison alone is ~170 us — dominates the rocprof
// top-5); the kernel itself is ~60 us vs a 43 us 272 MB streaming floor.
// This round: block-local contiguous output chunks (each block owns 32 KiB;
// each unrolled store is a contiguous 1 KiB wave segment at constant offset
// from one base) for DRAM page locality + cheaper addressing, replacing the
// 32-MB-stride round-robin.

typedef float v4f __attribute__((ext_vector_type(4)));

constexpr int ITER = 8;   // quarter-rows (float4 stores) per thread

__global__ __launch_bounds__(256) void encoder_kernel(
    const float* __restrict__ x, float* __restrict__ out, int nquarters)
{
    // Block-local contiguous chunk: block b owns quarters [b*2048, b*2048+2048).
    const int base_q = blockIdx.x * (256 * ITER) + threadIdx.x;

    constexpr uint32_t M = 13176795u;                        // mantissa of f32(2pi)
    constexpr uint64_t G = 0xFFFFFFFFFFFFFFFFull / M + 1ull; // ceil(2^64/M)

    #pragma unroll
    for (int j = 0; j < ITER; ++j) {
        int idx = base_q + j * 256;             // contiguous 1 KiB per wave-store
        if (idx >= nquarters) continue;         // no tail at bench shape
        int n = idx >> 2;                       // row
        int qpart = idx & 3;                    // which float4 of the 16-col row

        float xv = x[n];
        float tv = 6.28318530717958647692f * xv;   // 0x40C90FDB * xv, RN

        uint32_t bits = __float_as_uint(tv);
        int E = (int)(bits >> 23) - 127;
        uint32_t mant = (bits & 0x7FFFFFu) | 0x800000u;

        uint32_t q = (uint32_t)__umul64hi(((uint64_t)mant) << 15, G);
        int base = 16 - E;                      // bit for col c: s = base-(c-1)

        int c0 = qpart << 2;
        v4f res;
        #pragma unroll
        for (int k = 0; k < 4; ++k) {
            int c = c0 + k;
            float v;
            if (c == 0) {
                v = xv;                         // pass-through column
            } else {
                uint32_t s = (uint32_t)(base - (c - 1));
                s = s > 31u ? 31u : s;          // q < 2^16: clamp is safe
                uint32_t bit = (q >> s) & 1u;
                v = __uint_as_float(0x3F800000u | (bit << 31)); // ±1.0f
            }
            res[k] = v;
        }
        __builtin_nontemporal_store(res, reinterpret_cast<v4f*>(out) + idx);
    }
}

extern "C" void kernel_launch(void* const* d_in, const int* in_sizes, int n_in,
                              void* d_out, int out_size, void* d_ws, size_t ws_size,
                              hipStream_t stream) {
    const float* x = (const float*)d_in[0];
    float* out = (float*)d_out;
    int nrows = in_sizes[0];                    // 4194304
    int nquarters = nrows * 4;                  // 16,777,216 float4 stores
    int per_block = 256 * ITER;                 // 2048 quarters / block
    int blocks = (nquarters + per_block - 1) / per_block;   // 8192 exact
    encoder_kernel<<<blocks, 256, 0, stream>>>(x, out, nquarters);
}

// Round 5
// 276.077 us; speedup vs baseline: 1.0107x; 1.0107x over previous
//
#include <hip/hip_runtime.h>
#include <stdint.h>

// Encoder: out[n][0] = x[n]; out[n][1+i] = square(2*pi * x[n] * 2^i), i=0..14.
//
// Bit-exact replication of the f32 JAX reference:
//   t = RN32(f32(2pi) * x); p = t * 2^i (exact pow2 scale);
//   sq = fmodf(p, f32(2pi)) < f32(pi) ? +1 : -1.
// f32(2pi) = M*2^-21, f32(pi) = M*2^-22, M = 13176795 (same 24-bit mantissa).
// With t = mant*2^(E-23):  fmod(t*2^i, 2pif) < pif  <=>  floor(t*2^i/pif) even
//   <=>  bit (E-1+i) of the binary expansion of mant/M is 0.
// q = floor(mant*2^15 / M) (exact via magic multiply: err < 2^-24 < 1/M) holds
// those bits; q < 2^16, so clamping the shift to 31 yields bit=0 for any
// out-of-range index (covers x=0 / tiny x where E is very negative).
//
// Perf model (R3/R4 post-mortem): dur_us carries ~217 us of fixed harness
// poison/restore fills (1 GiB ws poison ~170 us dominates rocprof top-5);
// kernel portion ~60 us vs 43 us floor (272 MB @ 6.3 TB/s — the rate the
// harness's own fill kernel achieves). R4's block-local chunking was neutral
// => store-address pattern is not the gap. This round attacks the two
// remaining deltas vs the pure-fill kernel:
//   (a) batch all 8 x-loads before any store (kills per-iter read/write
//       interleave + dependent load->store chains);
//   (b) plain writeback stores instead of nontemporal (the 6.3 TB/s fill
//       uses plain stores; nt bypasses L2 write-combining).

typedef float v4f __attribute__((ext_vector_type(4)));

constexpr int ITER = 8;   // quarter-rows (float4 stores) per thread

__global__ __launch_bounds__(256) void encoder_kernel(
    const float* __restrict__ x, float* __restrict__ out, int nquarters)
{
    // Block-local contiguous chunk: block b owns quarters [b*2048, b*2048+2048).
    const int base_q = blockIdx.x * (256 * ITER) + threadIdx.x;

    constexpr uint32_t M = 13176795u;                        // mantissa of f32(2pi)
    constexpr uint64_t G = 0xFFFFFFFFFFFFFFFFull / M + 1ull; // ceil(2^64/M)

    // Phase 1: all loads up front — 8 independent reads in flight.
    float xv[ITER];
    #pragma unroll
    for (int j = 0; j < ITER; ++j) {
        int idx = base_q + j * 256;
        xv[j] = (idx < nquarters) ? x[idx >> 2] : 0.0f;
    }

    // Phase 2: compute + back-to-back streaming stores.
    #pragma unroll
    for (int j = 0; j < ITER; ++j) {
        int idx = base_q + j * 256;
        if (idx >= nquarters) continue;         // no tail at bench shape
        int qpart = idx & 3;                    // which float4 of the 16-col row

        float xj = xv[j];
        float tv = 6.28318530717958647692f * xj;   // 0x40C90FDB * xj, RN

        uint32_t bits = __float_as_uint(tv);
        int E = (int)(bits >> 23) - 127;
        uint32_t mant = (bits & 0x7FFFFFu) | 0x800000u;

        uint32_t q = (uint32_t)__umul64hi(((uint64_t)mant) << 15, G);
        int base = 16 - E;                      // bit for col c: s = base-(c-1)

        int c0 = qpart << 2;
        v4f res;
        #pragma unroll
        for (int k = 0; k < 4; ++k) {
            int c = c0 + k;
            float v;
            if (c == 0) {
                v = xj;                         // pass-through column
            } else {
                uint32_t s = (uint32_t)(base - (c - 1));
                s = s > 31u ? 31u : s;          // q < 2^16: clamp is safe
                uint32_t bit = (q >> s) & 1u;
                v = __uint_as_float(0x3F800000u | (bit << 31)); // ±1.0f
            }
            res[k] = v;
        }
        reinterpret_cast<v4f*>(out)[idx] = res; // plain writeback store
    }
}

extern "C" void kernel_launch(void* const* d_in, const int* in_sizes, int n_in,
                              void* d_out, int out_size, void* d_ws, size_t ws_size,
                              hipStream_t stream) {
    const float* x = (const float*)d_in[0];
    float* out = (float*)d_out;
    int nrows = in_sizes[0];                    // 4194304
    int nquarters = nrows * 4;                  // 16,777,216 float4 stores
    int per_block = 256 * ITER;                 // 2048 quarters / block
    int blocks = (nquarters + per_block - 1) / per_block;   // 8192 exact
    encoder_kernel<<<blocks, 256, 0, stream>>>(x, out, nquarters);
}